// Round 10
// baseline (1064.671 us; speedup 1.0000x reference)
//
#include <hip/hip_runtime.h>

#define NTIPS 512
#define DIM   510                    // internal nodes = ntips - 2
#define TOTAL 1022
#define BS    64
#define ITERS 50
#define SLABF 16                     // features per workgroup slab
#define NSLAB (NTIPS / SLABF)        // 32 slabs per tree
#define NWG   (BS * NSLAB)           // 2048 workgroups
#define NPART ((size_t)ITERS * BS * NSLAB)

typedef unsigned short u16;
typedef unsigned int   u32;

// bf16 RNE helpers — bit-identical to the validated R6..R9 arithmetic
__device__ __forceinline__ u16 f2bf(float x) {
    u32 u = __float_as_uint(x);
    return (u16)((u + 0x7FFFu + ((u >> 16) & 1u)) >> 16);
}
__device__ __forceinline__ float bf2f(u16 h) {
    return __uint_as_float(((u32)h) << 16);
}
__device__ __forceinline__ float bflo(u32 p) { return __uint_as_float(p << 16); }
__device__ __forceinline__ float bfhi(u32 p) { return __uint_as_float(p & 0xFFFF0000u); }

#if defined(__has_builtin)
#  if __has_builtin(__builtin_amdgcn_cvt_pk_bf16_f32)
#    define HAVE_PKBF 1
#  endif
#endif
#ifdef HAVE_PKBF
typedef __bf16 bf16x2 __attribute__((ext_vector_type(2)));
__device__ __forceinline__ u32 pkbf(float a, float b) {   // lo=a, hi=b, RNE
    bf16x2 r = __builtin_amdgcn_cvt_pk_bf16_f32(a, b);
    return __builtin_bit_cast(u32, r);
}
#else
__device__ __forceinline__ u32 pkbf(float a, float b) {
    return (u32)f2bf(a) | ((u32)f2bf(b) << 16);
}
#endif

// exact f32 RN division by 3 (correctly rounded via double)
__device__ __forceinline__ float div3(float x) {
    return (float)((double)x * (1.0 / 3.0));
}

// swizzled slab offset of (row i, feature-quad base lbase): spreads gather
// banks over 4 bits of the row index instead of 2 -> ~2-way max (free)
__device__ __forceinline__ int lds_off(int i, int lbase) {
    return i * SLABF + (lbase ^ (i & 12));
}

__global__ __launch_bounds__(256) void zero_kernel(float* __restrict__ p) {
    size_t g = (size_t)blockIdx.x * 256 + threadIdx.x;
    if (g < NPART) p[g] = 0.f;
}

// ---------------------------------------------------------------------------
// phaseA: full (up to 50-step) trajectory per slab in LDS, per-step slab delta
// to partials. Early-exit on exact period-2 cycle (X_s == X_{s-2}) with
// analytic fill of remaining partials, or on frozen slab (dtot==0, prezeroed).
// ---------------------------------------------------------------------------
__global__ __launch_bounds__(256, 4) void phaseA_kernel(
        const int* __restrict__ edge, float* __restrict__ partials) {
    __shared__ u16 Xs[2][DIM * SLABF];
    __shared__ ushort4 eL[DIM];
    __shared__ float red4[4];
    __shared__ int flagz[2];

    const int wg = blockIdx.x, b = wg >> 5, sl = wg & 31;
    const int tid = threadIdx.x;
    const int rg = tid >> 2;               // row engine 0..63
    const int lbase = (tid & 3) << 2;      // slab-local feature quad base
    const int fbase = sl * SLABF + lbase;  // global feature of elem 0

    for (int j = tid; j < DIM; j += 256) {
        const int* ep = edge + ((size_t)b * TOTAL + NTIPS + j) * 3;
        ushort4 t; t.x = (u16)ep[0]; t.y = (u16)ep[1]; t.z = (u16)ep[2]; t.w = 0;
        eL[j] = t;
    }
    for (int j = tid; j < DIM * SLABF / 2; j += 256)
        reinterpret_cast<u32*>(Xs[0])[j] = 0x3B003B00u;   // bf16(1/512) pairs
    if (tid < 2) flagz[tid] = 0;
    __syncthreads();

    float dprev = 0.f;
    for (int s = 1; s <= ITERS; ++s) {
        const u16* __restrict__ src = Xs[(s - 1) & 1];
        u16* __restrict__ dst = Xs[s & 1];
        float dacc = 0.f;
        u32 neq = 0u;
        for (int i = rg; i < DIM; i += 64) {
            const ushort4 ev = eL[i];
            float a0 = 0.f, a1 = 0.f, a2 = 0.f, a3 = 0.f;
            #pragma unroll
            for (int k = 0; k < 3; ++k) {
                const int ek = (k == 0) ? (int)ev.x : (k == 1) ? (int)ev.y
                                                               : (int)ev.z;
                const bool inter = (ek >= NTIPS);
                const int ro = inter ? (ek - NTIPS) : 0;
                const ushort4 g = *reinterpret_cast<const ushort4*>(
                    src + lds_off(ro, lbase));
                const int dlt = ek - fbase;
                a0 += inter ? bf2f(g.x) : ((dlt == 0) ? 1.f : 0.f);
                a1 += inter ? bf2f(g.y) : ((dlt == 1) ? 1.f : 0.f);
                a2 += inter ? bf2f(g.z) : ((dlt == 2) ? 1.f : 0.f);
                a3 += inter ? bf2f(g.w) : ((dlt == 3) ? 1.f : 0.f);
            }
            uint2 nv;
            nv.x = pkbf(div3(a0), div3(a1));
            nv.y = pkbf(div3(a2), div3(a3));
            const int lio = lds_off(i, lbase);
            const ushort4 ov = *reinterpret_cast<const ushort4*>(src + lio);
            const u32 d01 = pkbf(bflo(nv.x) - bf2f(ov.x),
                                 bfhi(nv.x) - bf2f(ov.y));
            const u32 d23 = pkbf(bflo(nv.y) - bf2f(ov.z),
                                 bfhi(nv.y) - bf2f(ov.w));
            dacc += fabsf(bflo(d01));
            dacc += fabsf(bfhi(d01));
            dacc += fabsf(bflo(d23));
            dacc += fabsf(bfhi(d23));
            if (s >= 2) {                  // cycle check vs X_{s-2} (old dst)
                const uint2 od = *reinterpret_cast<const uint2*>(dst + lio);
                neq |= (nv.x ^ od.x) | (nv.y ^ od.y);
            }
            *reinterpret_cast<uint2*>(dst + lio) = nv;
        }
        #pragma unroll
        for (int off = 32; off > 0; off >>= 1) dacc += __shfl_down(dacc, off);
        if ((tid & 63) == 0) red4[tid >> 6] = dacc;
        if (neq) flagz[s & 1] = 1;         // benign all-write-1 race
        if (tid == 0) flagz[(s + 1) & 1] = 0;
        __syncthreads();
        const float dtot = ((red4[0] + red4[1]) + red4[2]) + red4[3];
        const int moved = flagz[s & 1];
        if (tid == 0)
            partials[((size_t)(s - 1) * BS + b) * NSLAB + sl] = dtot;
        if (s >= 2 && !moved) {            // X_s == X_{s-2}: period-2 forever
            if (tid == 0)                  // delta_{s'} = delta_{s'-2}
                for (int s2 = s + 1; s2 <= ITERS; ++s2)
                    partials[((size_t)(s2 - 1) * BS + b) * NSLAB + sl] =
                        ((s2 - s) & 1) ? dprev : dtot;
            break;
        }
        if (dtot == 0.f) break;            // frozen: rest prezeroed
        dprev = dtot;
        __syncthreads();                   // protect red4/flagz reuse
    }
}

// ---------------------------------------------------------------------------
// findS: one wave. S = first s with all trees' bf16(lnorm_s) <= bf16(1e-5).
// ---------------------------------------------------------------------------
__global__ void findS_kernel(const float* __restrict__ partials,
                             int* __restrict__ ctrl) {
    const int lane = threadIdx.x;          // 64 lanes = trees
    const float tol_bf = bf2f(f2bf(1e-5f));
    int S = ITERS;
    for (int s = 1; s <= ITERS; ++s) {
        const float* p = partials + ((size_t)(s - 1) * BS + lane) * NSLAB;
        float t = 0.f;
        #pragma unroll
        for (int k = 0; k < NSLAB; ++k) t += p[k];
        const float lnorm = bf2f(f2bf(t / 261120.0f));
        if (__ballot(lnorm > tol_bf) == 0ULL) { S = s; break; }
    }
    if (lane == 0) ctrl[0] = S;
}

// ---------------------------------------------------------------------------
// phaseC: identical trajectory, exactly S steps, no delta bookkeeping;
// output fp32 column slab from buffer[S&1].
// ---------------------------------------------------------------------------
__global__ __launch_bounds__(256, 4) void phaseC_kernel(
        const int* __restrict__ edge, const int* __restrict__ ctrl,
        float* __restrict__ out) {
    __shared__ u16 Xs[2][DIM * SLABF];
    __shared__ ushort4 eL[DIM];

    const int wg = blockIdx.x, b = wg >> 5, sl = wg & 31;
    const int tid = threadIdx.x;
    const int rg = tid >> 2;
    const int lbase = (tid & 3) << 2;
    const int fbase = sl * SLABF + lbase;

    for (int j = tid; j < DIM; j += 256) {
        const int* ep = edge + ((size_t)b * TOTAL + NTIPS + j) * 3;
        ushort4 t; t.x = (u16)ep[0]; t.y = (u16)ep[1]; t.z = (u16)ep[2]; t.w = 0;
        eL[j] = t;
    }
    for (int j = tid; j < DIM * SLABF / 2; j += 256)
        reinterpret_cast<u32*>(Xs[0])[j] = 0x3B003B00u;
    const int S = ctrl[0];
    __syncthreads();

    for (int s = 1; s <= S; ++s) {
        const u16* __restrict__ src = Xs[(s - 1) & 1];
        u16* __restrict__ dst = Xs[s & 1];
        for (int i = rg; i < DIM; i += 64) {
            const ushort4 ev = eL[i];
            float a0 = 0.f, a1 = 0.f, a2 = 0.f, a3 = 0.f;
            #pragma unroll
            for (int k = 0; k < 3; ++k) {
                const int ek = (k == 0) ? (int)ev.x : (k == 1) ? (int)ev.y
                                                               : (int)ev.z;
                const bool inter = (ek >= NTIPS);
                const int ro = inter ? (ek - NTIPS) : 0;
                const ushort4 g = *reinterpret_cast<const ushort4*>(
                    src + lds_off(ro, lbase));
                const int dlt = ek - fbase;
                a0 += inter ? bf2f(g.x) : ((dlt == 0) ? 1.f : 0.f);
                a1 += inter ? bf2f(g.y) : ((dlt == 1) ? 1.f : 0.f);
                a2 += inter ? bf2f(g.z) : ((dlt == 2) ? 1.f : 0.f);
                a3 += inter ? bf2f(g.w) : ((dlt == 3) ? 1.f : 0.f);
            }
            uint2 nv;
            nv.x = pkbf(div3(a0), div3(a1));
            nv.y = pkbf(div3(a2), div3(a3));
            *reinterpret_cast<uint2*>(dst + lds_off(i, lbase)) = nv;
        }
        __syncthreads();
    }

    const u16* fin = Xs[S & 1];            // X_S
    for (int r = rg; r < TOTAL; r += 64) {
        float4 v;
        if (r < NTIPS) {
            v.x = (r == fbase + 0) ? 1.f : 0.f;
            v.y = (r == fbase + 1) ? 1.f : 0.f;
            v.z = (r == fbase + 2) ? 1.f : 0.f;
            v.w = (r == fbase + 3) ? 1.f : 0.f;
        } else {
            const ushort4 g = *reinterpret_cast<const ushort4*>(
                fin + lds_off(r - NTIPS, lbase));
            v.x = bf2f(g.x); v.y = bf2f(g.y); v.z = bf2f(g.z); v.w = bf2f(g.w);
        }
        *reinterpret_cast<float4*>(
            out + ((size_t)b * TOTAL + r) * NTIPS + fbase) = v;
    }
}

extern "C" void kernel_launch(void* const* d_in, const int* in_sizes, int n_in,
                              void* d_out, int out_size, void* d_ws, size_t ws_size,
                              hipStream_t stream) {
    const int* edge = (const int*)d_in[1];       // (BS, TOTAL, 3) int32
    float* out = (float*)d_out;                  // (BS, TOTAL, 512) fp32

    float* partials = (float*)d_ws;              // [ITERS][BS][NSLAB] f32
    int*   ctrl     = (int*)((char*)d_ws + NPART * sizeof(float));

    zero_kernel<<<(unsigned)((NPART + 255) / 256), 256, 0, stream>>>(partials);
    phaseA_kernel<<<NWG, 256, 0, stream>>>(edge, partials);
    findS_kernel<<<1, 64, 0, stream>>>(partials, ctrl);
    phaseC_kernel<<<NWG, 256, 0, stream>>>(edge, ctrl, out);
}

// Round 11
// 599.367 us; speedup vs baseline: 1.7763x; 1.7763x over previous
//
#include <hip/hip_runtime.h>

#define NTIPS 512
#define DIM   510                     // internal nodes = ntips - 2
#define TOTAL 1022
#define BS    64
#define ITERS 50
#define SLABF 16                      // features per workgroup slab
#define NSLAB 32
#define NWG   (BS * NSLAB)            // 2048 workgroups
#define NPART ((size_t)ITERS * BS * NSLAB)

#define ROWEL 16                      // u16 elems per row-slab (32 B)
#define XSEC   (DIM * ROWEL)          // 8160 u16: evolving X section
#define ONEOFF XSEC                   // 16 one-hot const rows
#define ZROW   (XSEC + 16 * ROWEL)    // all-zero const row
#define BSTRIDE (XSEC + 17 * ROWEL)   // 8432 u16 per buffer (const dup/buffer)

typedef unsigned short u16;
typedef unsigned int   u32;

// bf16 RNE helpers — bit-identical to validated R6..R10 arithmetic
__device__ __forceinline__ u16 f2bf(float x) {
    u32 u = __float_as_uint(x);
    return (u16)((u + 0x7FFFu + ((u >> 16) & 1u)) >> 16);
}
__device__ __forceinline__ float bf2f(u16 h) { return __uint_as_float(((u32)h) << 16); }
__device__ __forceinline__ float bflo(u32 p) { return __uint_as_float(p << 16); }
__device__ __forceinline__ float bfhi(u32 p) { return __uint_as_float(p & 0xFFFF0000u); }

#if defined(__has_builtin)
#  if __has_builtin(__builtin_amdgcn_cvt_pk_bf16_f32)
#    define HAVE_PKBF 1
#  endif
#endif
#ifdef HAVE_PKBF
typedef __bf16 bf16x2 __attribute__((ext_vector_type(2)));
__device__ __forceinline__ u32 pkbf(float a, float b) {   // lo=a, hi=b, RNE
    bf16x2 r = __builtin_amdgcn_cvt_pk_bf16_f32(a, b);
    return __builtin_bit_cast(u32, r);
}
#else
__device__ __forceinline__ u32 pkbf(float a, float b) {
    return (u32)f2bf(a) | ((u32)f2bf(b) << 16);
}
#endif

// exact f32 RN division by 3 (correctly rounded via double)
__device__ __forceinline__ float div3(float x) {
    return (float)((double)x * (1.0 / 3.0));
}

// Precompute per-thread register-resident LDS offsets (u16 units, buffer-rel).
// Every neighbor (internal / in-slab leaf / out-slab leaf) maps to a slot:
// X row, one-hot const row, or zero const row -> unconditional gathers.
__device__ __forceinline__ void make_offsets(const int* __restrict__ edge,
        int b, int sl, int rg, int lbase, int nr,
        u32 offA[8][3], u32 rowo[8]) {
    #pragma unroll
    for (int k = 0; k < 8; ++k) {
        if (k < nr) {
            const int i = rg + 64 * k;
            rowo[k] = (u32)(i * ROWEL + lbase);
            const int* ep = edge + ((size_t)b * TOTAL + NTIPS + i) * 3;
            #pragma unroll
            for (int t = 0; t < 3; ++t) {
                const int e = ep[t];
                u32 off;
                if (e >= NTIPS)            off = (u32)((e - NTIPS) * ROWEL);
                else if ((e >> 4) == sl)   off = (u32)(ONEOFF + (e & 15) * ROWEL);
                else                       off = (u32)ZROW;
                offA[k][t] = off + (u32)lbase;
            }
        }
    }
}

// one row-quad update: ((g0 + g1) + g2) per element, /3 exact, pack bf16
__device__ __forceinline__ uint2 step_row(const u16* __restrict__ src,
                                          u32 o0, u32 o1, u32 o2) {
    const ushort4 g0 = *reinterpret_cast<const ushort4*>(src + o0);
    const ushort4 g1 = *reinterpret_cast<const ushort4*>(src + o1);
    const ushort4 g2 = *reinterpret_cast<const ushort4*>(src + o2);
    const float a0 = (bf2f(g0.x) + bf2f(g1.x)) + bf2f(g2.x);
    const float a1 = (bf2f(g0.y) + bf2f(g1.y)) + bf2f(g2.y);
    const float a2 = (bf2f(g0.z) + bf2f(g1.z)) + bf2f(g2.z);
    const float a3 = (bf2f(g0.w) + bf2f(g1.w)) + bf2f(g2.w);
    uint2 r;
    r.x = pkbf(div3(a0), div3(a1));
    r.y = pkbf(div3(a2), div3(a3));
    return r;
}

__device__ __forceinline__ void init_const_rows(u16* X, int tid) {
    for (int j = tid; j < 17 * ROWEL; j += 256) {
        const int row = j >> 4, col = j & 15;
        const u16 v = (row == col) ? (u16)0x3F80 : (u16)0;  // row 16 = zeros
        X[ONEOFF + j] = v;
        X[BSTRIDE + ONEOFF + j] = v;
    }
}

__global__ __launch_bounds__(256) void zero_kernel(float* __restrict__ p) {
    size_t g = (size_t)blockIdx.x * 256 + threadIdx.x;
    if (g < NPART) p[g] = 0.f;
}

// ---------------------------------------------------------------------------
// phaseA: 50-step trajectory per slab in LDS; per-step slab delta -> partials;
// snapshots of X_16/X_32/X_48 to gmem; freeze-break (dtot==0) forward-fills.
// ---------------------------------------------------------------------------
__global__ __launch_bounds__(256, 4) void phaseA_kernel(
        const int* __restrict__ edge, float* __restrict__ partials,
        u16* __restrict__ snap16, u16* __restrict__ snap32,
        u16* __restrict__ snap48) {
    __shared__ u16 X[2 * BSTRIDE];
    __shared__ float redL[2][4];

    const int wg = blockIdx.x, b = wg >> 5, sl = wg & 31;
    const int tid = threadIdx.x, rg = tid >> 2, lbase = (tid & 3) << 2;
    const int nr = (rg < 62) ? 8 : 7;

    u32 offA[8][3], rowo[8];
    make_offsets(edge, b, sl, rg, lbase, nr, offA, rowo);

    for (int j = tid; j < XSEC / 2; j += 256)
        reinterpret_cast<u32*>(X)[j] = 0x3B003B00u;         // X0 = bf16(1/512)
    init_const_rows(X, tid);
    __syncthreads();

    for (int s = 1; s <= ITERS; ++s) {
        const u16* src = X + ((s - 1) & 1) * BSTRIDE;
        u16* dst = X + (s & 1) * BSTRIDE;
        float dacc = 0.f;
        #pragma unroll
        for (int k = 0; k < 8; ++k) if (k < nr) {
            const uint2 nv = step_row(src, offA[k][0], offA[k][1], offA[k][2]);
            const ushort4 ov = *reinterpret_cast<const ushort4*>(src + rowo[k]);
            *reinterpret_cast<uint2*>(dst + rowo[k]) = nv;
            const u32 d01 = pkbf(bflo(nv.x) - bf2f(ov.x),
                                 bfhi(nv.x) - bf2f(ov.y));
            const u32 d23 = pkbf(bflo(nv.y) - bf2f(ov.z),
                                 bfhi(nv.y) - bf2f(ov.w));
            dacc += fabsf(bflo(d01));
            dacc += fabsf(bfhi(d01));
            dacc += fabsf(bflo(d23));
            dacc += fabsf(bfhi(d23));
        }
        #pragma unroll
        for (int off = 32; off > 0; off >>= 1) dacc += __shfl_down(dacc, off);
        if ((tid & 63) == 0) redL[s & 1][tid >> 6] = dacc;
        __syncthreads();
        const float dtot = ((redL[s & 1][0] + redL[s & 1][1])
                            + redL[s & 1][2]) + redL[s & 1][3];
        if (tid == 0)
            partials[((size_t)(s - 1) * BS + b) * NSLAB + sl] = dtot;

        const bool frozen = (dtot == 0.f);
        #define WRITE_SNAP(gm) { \
            u16* gbase = (gm) + ((size_t)b * DIM) * NTIPS + sl * SLABF + lbase; \
            _Pragma("unroll") for (int k = 0; k < 8; ++k) if (k < nr) { \
                const int i = rg + 64 * k; \
                *reinterpret_cast<ushort4*>(gbase + (size_t)i * NTIPS) = \
                    *reinterpret_cast<const ushort4*>(dst + rowo[k]); } }
        if (s == 16 || (frozen && s < 16)) WRITE_SNAP(snap16);
        if (s == 32 || (frozen && s < 32)) WRITE_SNAP(snap32);
        if (s == 48 || (frozen && s < 48)) WRITE_SNAP(snap48);
        if (frozen) break;   // X fixed: remaining partials prezeroed
    }
}

// ---------------------------------------------------------------------------
// findS: S = first s with all trees' bf16(lnorm_s) <= bf16(1e-5); pick
// checkpoint c = largest of {0,16,32,48} <= S.
// ---------------------------------------------------------------------------
__global__ void findS_kernel(const float* __restrict__ partials,
                             int* __restrict__ ctrl) {
    const int lane = threadIdx.x;          // 64 lanes = trees
    const float tol_bf = bf2f(f2bf(1e-5f));
    int S = ITERS;
    for (int s = 1; s <= ITERS; ++s) {
        const float* p = partials + ((size_t)(s - 1) * BS + lane) * NSLAB;
        float t = 0.f;
        #pragma unroll
        for (int k = 0; k < NSLAB; ++k) t += p[k];
        const float lnorm = bf2f(f2bf(t / 261120.0f));
        if (__ballot(lnorm > tol_bf) == 0ULL) { S = s; break; }
    }
    if (lane == 0) {
        ctrl[0] = S;
        ctrl[1] = (S >= 48) ? 48 : (S >= 32) ? 32 : (S >= 16) ? 16 : 0;
    }
}

// ---------------------------------------------------------------------------
// phaseC: resume from checkpoint c, run S-c steps, write bf16 X_S to finalX.
// Each wg reads/writes only its own (b, slab) slice -> no cross-wg races.
// ---------------------------------------------------------------------------
__global__ __launch_bounds__(256, 4) void phaseC_kernel(
        const int* __restrict__ edge, const int* __restrict__ ctrl,
        const u16* __restrict__ snap16, const u16* __restrict__ snap32,
        const u16* __restrict__ snap48, u16* __restrict__ finalX) {
    __shared__ u16 X[2 * BSTRIDE];

    const int wg = blockIdx.x, b = wg >> 5, sl = wg & 31;
    const int tid = threadIdx.x, rg = tid >> 2, lbase = (tid & 3) << 2;
    const int nr = (rg < 62) ? 8 : 7;

    u32 offA[8][3], rowo[8];
    make_offsets(edge, b, sl, rg, lbase, nr, offA, rowo);

    const int S = ctrl[0], c = ctrl[1];
    if (c == 0) {
        for (int j = tid; j < XSEC / 2; j += 256)
            reinterpret_cast<u32*>(X)[j] = 0x3B003B00u;
    } else {
        const u16* gm = (c == 16) ? snap16 : (c == 32) ? snap32 : snap48;
        const u16* gbase = gm + ((size_t)b * DIM) * NTIPS + sl * SLABF + lbase;
        #pragma unroll
        for (int k = 0; k < 8; ++k) if (k < nr) {
            const int i = rg + 64 * k;
            *reinterpret_cast<ushort4*>(X + rowo[k]) =
                *reinterpret_cast<const ushort4*>(gbase + (size_t)i * NTIPS);
        }
    }
    init_const_rows(X, tid);
    __syncthreads();

    const int T = S - c;
    for (int t = 1; t <= T; ++t) {
        const u16* src = X + ((t - 1) & 1) * BSTRIDE;
        u16* dst = X + (t & 1) * BSTRIDE;
        #pragma unroll
        for (int k = 0; k < 8; ++k) if (k < nr)
            *reinterpret_cast<uint2*>(dst + rowo[k]) =
                step_row(src, offA[k][0], offA[k][1], offA[k][2]);
        __syncthreads();
    }

    const u16* fin = X + (T & 1) * BSTRIDE;
    u16* gbase = finalX + ((size_t)b * DIM) * NTIPS + sl * SLABF + lbase;
    #pragma unroll
    for (int k = 0; k < 8; ++k) if (k < nr) {
        const int i = rg + 64 * k;
        *reinterpret_cast<ushort4*>(gbase + (size_t)i * NTIPS) =
            *reinterpret_cast<const ushort4*>(fin + rowo[k]);
    }
}

// ---------------------------------------------------------------------------
// convert: d_out fp32 = [identity ; f32(bf16 finalX)] per batch.
// ---------------------------------------------------------------------------
__global__ __launch_bounds__(64) void convert_kernel(
        const u16* __restrict__ finalX, float* __restrict__ out) {
    const int r = blockIdx.x;              // 0..1021
    const int b = blockIdx.y;
    const int f0 = threadIdx.x << 3;       // 8 floats per thread
    float4 lo, hi;
    if (r < NTIPS) {
        lo.x = (r == f0 + 0) ? 1.f : 0.f;
        lo.y = (r == f0 + 1) ? 1.f : 0.f;
        lo.z = (r == f0 + 2) ? 1.f : 0.f;
        lo.w = (r == f0 + 3) ? 1.f : 0.f;
        hi.x = (r == f0 + 4) ? 1.f : 0.f;
        hi.y = (r == f0 + 5) ? 1.f : 0.f;
        hi.z = (r == f0 + 6) ? 1.f : 0.f;
        hi.w = (r == f0 + 7) ? 1.f : 0.f;
    } else {
        const u16* row = finalX + ((size_t)b * DIM + (r - NTIPS)) * NTIPS + f0;
        const ushort4 a = *reinterpret_cast<const ushort4*>(row);
        const ushort4 c = *reinterpret_cast<const ushort4*>(row + 4);
        lo.x = bf2f(a.x); lo.y = bf2f(a.y); lo.z = bf2f(a.z); lo.w = bf2f(a.w);
        hi.x = bf2f(c.x); hi.y = bf2f(c.y); hi.z = bf2f(c.z); hi.w = bf2f(c.w);
    }
    float* drow = out + ((size_t)b * TOTAL + r) * NTIPS + f0;
    *reinterpret_cast<float4*>(drow)     = lo;
    *reinterpret_cast<float4*>(drow + 4) = hi;
}

extern "C" void kernel_launch(void* const* d_in, const int* in_sizes, int n_in,
                              void* d_out, int out_size, void* d_ws, size_t ws_size,
                              hipStream_t stream) {
    const int* edge = (const int*)d_in[1];       // (BS, TOTAL, 3) int32
    float* out = (float*)d_out;

    const size_t XB = (size_t)BS * DIM * NTIPS;  // 16,711,680 u16 elems
    u16*   snap16 = (u16*)d_ws;                  // also final X region
    float* partials = (float*)((char*)d_ws + XB * sizeof(u16));
    int*   ctrl = (int*)(partials + NPART);

    u16* snap32 = (u16*)d_out;                   // d_out scratch during A/C
    u16* snap48 = (u16*)d_out + XB;

    zero_kernel<<<(unsigned)((NPART + 255) / 256), 256, 0, stream>>>(partials);
    phaseA_kernel<<<NWG, 256, 0, stream>>>(edge, partials, snap16, snap32, snap48);
    findS_kernel<<<1, 64, 0, stream>>>(partials, ctrl);
    phaseC_kernel<<<NWG, 256, 0, stream>>>(edge, ctrl, snap16, snap32, snap48,
                                           snap16);
    convert_kernel<<<dim3(TOTAL, BS), 64, 0, stream>>>(snap16, out);
}

// Round 12
// 311.494 us; speedup vs baseline: 3.4180x; 1.9242x over previous
//
#include <hip/hip_runtime.h>

#define NTIPS 512
#define DIM   510                     // internal nodes = ntips - 2
#define TOTAL 1022
#define BS    64
#define ITERS 50
#define SLABF 16                      // features per workgroup slab
#define NSLAB 32
#define NWG   (BS * NSLAB)            // 2048 workgroups
#define NPART ((size_t)ITERS * BS * NSLAB)
#define WIDTH 10                      // steps per chunk
#define NCHUNK 5

#define ROWEL 16                      // u16 elems per row-slab (32 B)
#define XSEC   (DIM * ROWEL)          // evolving X section
#define ONEOFF XSEC                   // 16 one-hot const rows
#define ZROW   (XSEC + 16 * ROWEL)    // all-zero const row
#define BSTRIDE (XSEC + 17 * ROWEL)   // u16 per LDS buffer

typedef unsigned short u16;
typedef unsigned int   u32;

// bf16 RNE helpers — bit-identical to validated R6..R11 arithmetic
__device__ __forceinline__ u16 f2bf(float x) {
    u32 u = __float_as_uint(x);
    return (u16)((u + 0x7FFFu + ((u >> 16) & 1u)) >> 16);
}
__device__ __forceinline__ float bf2f(u16 h) { return __uint_as_float(((u32)h) << 16); }
__device__ __forceinline__ float bflo(u32 p) { return __uint_as_float(p << 16); }
__device__ __forceinline__ float bfhi(u32 p) { return __uint_as_float(p & 0xFFFF0000u); }

#if defined(__has_builtin)
#  if __has_builtin(__builtin_amdgcn_cvt_pk_bf16_f32)
#    define HAVE_PKBF 1
#  endif
#endif
#ifdef HAVE_PKBF
typedef __bf16 bf16x2 __attribute__((ext_vector_type(2)));
__device__ __forceinline__ u32 pkbf(float a, float b) {   // lo=a, hi=b, RNE
    bf16x2 r = __builtin_amdgcn_cvt_pk_bf16_f32(a, b);
    return __builtin_bit_cast(u32, r);
}
#else
__device__ __forceinline__ u32 pkbf(float a, float b) {
    return (u32)f2bf(a) | ((u32)f2bf(b) << 16);
}
#endif

// exact f32 RN division by 3 (correctly rounded via double) — validated chain
__device__ __forceinline__ float div3(float x) {
    return (float)((double)x * (1.0 / 3.0));
}

// register-resident gather offsets (u16 units, buffer-relative)
__device__ __forceinline__ void make_offsets(const int* __restrict__ edge,
        int b, int sl, int rg, int lbase, int nr, u32 offA[8][3]) {
    #pragma unroll
    for (int k = 0; k < 8; ++k) if (k < nr) {
        const int i = rg + 64 * k;
        const int* ep = edge + ((size_t)b * TOTAL + NTIPS + i) * 3;
        #pragma unroll
        for (int t = 0; t < 3; ++t) {
            const int e = ep[t];
            u32 off;
            if (e >= NTIPS)          off = (u32)((e - NTIPS) * ROWEL);
            else if ((e >> 4) == sl) off = (u32)(ONEOFF + (e & 15) * ROWEL);
            else                     off = (u32)ZROW;
            offA[k][t] = off + (u32)lbase;
        }
    }
}

// one row-quad update: ((g0 + g1) + g2), /3 exact, pack bf16
__device__ __forceinline__ uint2 step_row(const u16* __restrict__ src,
                                          u32 o0, u32 o1, u32 o2) {
    const ushort4 g0 = *reinterpret_cast<const ushort4*>(src + o0);
    const ushort4 g1 = *reinterpret_cast<const ushort4*>(src + o1);
    const ushort4 g2 = *reinterpret_cast<const ushort4*>(src + o2);
    const float a0 = (bf2f(g0.x) + bf2f(g1.x)) + bf2f(g2.x);
    const float a1 = (bf2f(g0.y) + bf2f(g1.y)) + bf2f(g2.y);
    const float a2 = (bf2f(g0.z) + bf2f(g1.z)) + bf2f(g2.z);
    const float a3 = (bf2f(g0.w) + bf2f(g1.w)) + bf2f(g2.w);
    uint2 r;
    r.x = pkbf(div3(a0), div3(a1));
    r.y = pkbf(div3(a2), div3(a3));
    return r;
}

__device__ __forceinline__ void init_const_rows(u16* X, int tid) {
    for (int j = tid; j < 17 * ROWEL; j += 256) {
        const int row = j >> 4, col = j & 15;
        const u16 v = (row == col) ? (u16)0x3F80 : (u16)0;  // row 16 = zeros
        X[ONEOFF + j] = v;
        X[BSTRIDE + ONEOFF + j] = v;
    }
}

// ---------------------------------------------------------------------------
// chunk q (1..5): steps 10(q-1)+1 .. 10q. Gated on not-yet-converged.
// Resumes from chunk q-1's snapshot (slot (q-1)&1: odd chunk -> snapD).
// Old row values carried in registers for the delta. Snapshot X_{10q} at end.
// ---------------------------------------------------------------------------
__global__ __launch_bounds__(256, 4) void chunk_kernel(
        const int* __restrict__ edge, float* __restrict__ partials,
        int* __restrict__ ctrl, u16* __restrict__ snapD,
        u16* __restrict__ snapW, int q) {
    if (q >= 2 && ctrl[2] != 0) return;          // converged: skip

    __shared__ u16 X[2 * BSTRIDE];
    __shared__ float redL[2][4];

    const int wg = blockIdx.x, b = wg >> 5, sl = wg & 31;
    const int tid = threadIdx.x, rg = tid >> 2, lbase = (tid & 3) << 2;
    const int nr = (rg < 62) ? 8 : 7;
    const int r0 = rg * ROWEL + lbase;           // own-row LDS base (k: +1024*k)

    if (q == 1 && wg == 0 && tid == 0) ctrl[2] = 0;   // clear poisoned flag

    u32 offA[8][3];
    make_offsets(edge, b, sl, rg, lbase, nr, offA);

    if (q == 1) {
        for (int j = tid; j < XSEC / 2; j += 256)
            reinterpret_cast<u32*>(X)[j] = 0x3B003B00u;   // X0 = bf16(1/512)
    } else {
        const u16* snap = ((q - 1) & 1) ? snapD : snapW;
        const u16* gb = snap + (size_t)b * DIM * NTIPS + sl * SLABF + lbase;
        #pragma unroll
        for (int k = 0; k < 8; ++k) if (k < nr)
            *reinterpret_cast<ushort4*>(X + r0 + (k << 10)) =
                *reinterpret_cast<const ushort4*>(gb + (size_t)(rg + 64 * k) * NTIPS);
    }
    init_const_rows(X, tid);

    // old-row f32 values in registers (own rows, written by self — no barrier)
    float oldf[8][4];
    #pragma unroll
    for (int k = 0; k < 8; ++k) if (k < nr) {
        const ushort4 ov = *reinterpret_cast<const ushort4*>(X + r0 + (k << 10));
        oldf[k][0] = bf2f(ov.x); oldf[k][1] = bf2f(ov.y);
        oldf[k][2] = bf2f(ov.z); oldf[k][3] = bf2f(ov.w);
    }
    __syncthreads();

    const int sBeg = (q - 1) * WIDTH + 1, sEnd = q * WIDTH;
    for (int s = sBeg; s <= sEnd; ++s) {
        const u16* src = X + ((s - sBeg) & 1) * BSTRIDE;
        u16* dst = X + ((s - sBeg + 1) & 1) * BSTRIDE;
        float dacc = 0.f;
        #pragma unroll
        for (int k = 0; k < 8; ++k) if (k < nr) {
            const uint2 nv = step_row(src, offA[k][0], offA[k][1], offA[k][2]);
            *reinterpret_cast<uint2*>(dst + r0 + (k << 10)) = nv;
            const float nf0 = bflo(nv.x), nf1 = bfhi(nv.x);
            const float nf2 = bflo(nv.y), nf3 = bfhi(nv.y);
            const u32 d01 = pkbf(nf0 - oldf[k][0], nf1 - oldf[k][1]);
            const u32 d23 = pkbf(nf2 - oldf[k][2], nf3 - oldf[k][3]);
            dacc += fabsf(bflo(d01));
            dacc += fabsf(bfhi(d01));
            dacc += fabsf(bflo(d23));
            dacc += fabsf(bfhi(d23));
            oldf[k][0] = nf0; oldf[k][1] = nf1;
            oldf[k][2] = nf2; oldf[k][3] = nf3;
        }
        #pragma unroll
        for (int off = 32; off > 0; off >>= 1) dacc += __shfl_down(dacc, off);
        if ((tid & 63) == 0) redL[s & 1][tid >> 6] = dacc;
        __syncthreads();
        if (tid == 0) {
            const float dtot = ((redL[s & 1][0] + redL[s & 1][1])
                                + redL[s & 1][2]) + redL[s & 1][3];
            partials[((size_t)(s - 1) * BS + b) * NSLAB + sl] = dtot;
        }
    }

    // snapshot X_{10q} to slot q&1 (odd -> snapD, even -> snapW)
    u16* snap = (q & 1) ? snapD : snapW;
    u16* gb = snap + (size_t)b * DIM * NTIPS + sl * SLABF + lbase;
    const u16* fin = X + ((sEnd - sBeg + 1) & 1) * BSTRIDE;
    #pragma unroll
    for (int k = 0; k < 8; ++k) if (k < nr)
        *reinterpret_cast<ushort4*>(gb + (size_t)(rg + 64 * k) * NTIPS) =
            *reinterpret_cast<const ushort4*>(fin + r0 + (k << 10));
}

// ---------------------------------------------------------------------------
// findS after chunk k: gate on found. Scan s=1..smax with the validated
// decision procedure; if converged set {S, c, found}. smax==50 forces S=50.
// ---------------------------------------------------------------------------
__global__ void findS_kernel(const float* __restrict__ partials,
                             int* __restrict__ ctrl, int smax) {
    if (ctrl[2] != 0) return;
    const int lane = threadIdx.x;                // 64 lanes = trees
    const float tol_bf = bf2f(f2bf(1e-5f));
    int S = -1;
    for (int s = 1; s <= smax; ++s) {
        const float* p = partials + ((size_t)(s - 1) * BS + lane) * NSLAB;
        float t = 0.f;
        #pragma unroll
        for (int k = 0; k < NSLAB; ++k) t += p[k];
        const float lnorm = bf2f(f2bf(t / 261120.0f));
        if (__ballot(lnorm > tol_bf) == 0ULL) { S = s; break; }
    }
    if (S < 0 && smax == ITERS) S = ITERS;       // cap at MAX_ITERS
    if (lane == 0 && S > 0) {
        ctrl[0] = S;
        ctrl[1] = WIDTH * ((S - 1) / WIDTH);     // checkpoint c < S
        ctrl[2] = 1;
    }
}

// ---------------------------------------------------------------------------
// phaseC: resume from X_c, run S-c (<=10) steps, write bf16 X_S to finalX.
// ---------------------------------------------------------------------------
__global__ __launch_bounds__(256, 4) void phaseC_kernel(
        const int* __restrict__ edge, const int* __restrict__ ctrl,
        const u16* __restrict__ snapD, const u16* __restrict__ snapW,
        u16* __restrict__ finalX) {
    __shared__ u16 X[2 * BSTRIDE];

    const int wg = blockIdx.x, b = wg >> 5, sl = wg & 31;
    const int tid = threadIdx.x, rg = tid >> 2, lbase = (tid & 3) << 2;
    const int nr = (rg < 62) ? 8 : 7;
    const int r0 = rg * ROWEL + lbase;

    u32 offA[8][3];
    make_offsets(edge, b, sl, rg, lbase, nr, offA);

    const int S = ctrl[0], c = ctrl[1];
    if (c == 0) {
        for (int j = tid; j < XSEC / 2; j += 256)
            reinterpret_cast<u32*>(X)[j] = 0x3B003B00u;
    } else {
        const u16* snap = ((c / WIDTH) & 1) ? snapD : snapW;
        const u16* gb = snap + (size_t)b * DIM * NTIPS + sl * SLABF + lbase;
        #pragma unroll
        for (int k = 0; k < 8; ++k) if (k < nr)
            *reinterpret_cast<ushort4*>(X + r0 + (k << 10)) =
                *reinterpret_cast<const ushort4*>(gb + (size_t)(rg + 64 * k) * NTIPS);
    }
    init_const_rows(X, tid);
    __syncthreads();

    const int T = S - c;                         // 1..10
    for (int t = 1; t <= T; ++t) {
        const u16* src = X + ((t - 1) & 1) * BSTRIDE;
        u16* dst = X + (t & 1) * BSTRIDE;
        #pragma unroll
        for (int k = 0; k < 8; ++k) if (k < nr)
            *reinterpret_cast<uint2*>(dst + r0 + (k << 10)) =
                step_row(src, offA[k][0], offA[k][1], offA[k][2]);
        __syncthreads();
    }

    const u16* fin = X + (T & 1) * BSTRIDE;
    u16* gb = finalX + (size_t)b * DIM * NTIPS + sl * SLABF + lbase;
    #pragma unroll
    for (int k = 0; k < 8; ++k) if (k < nr)
        *reinterpret_cast<ushort4*>(gb + (size_t)(rg + 64 * k) * NTIPS) =
            *reinterpret_cast<const ushort4*>(fin + r0 + (k << 10));
}

// ---------------------------------------------------------------------------
// convert: d_out fp32 = [identity ; f32(bf16 finalX)] per batch.
// ---------------------------------------------------------------------------
__global__ __launch_bounds__(64) void convert_kernel(
        const u16* __restrict__ finalX, float* __restrict__ out) {
    const int r = blockIdx.x;                    // 0..1021
    const int b = blockIdx.y;
    const int f0 = threadIdx.x << 3;             // 8 floats per thread
    float4 lo, hi;
    if (r < NTIPS) {
        lo.x = (r == f0 + 0) ? 1.f : 0.f;
        lo.y = (r == f0 + 1) ? 1.f : 0.f;
        lo.z = (r == f0 + 2) ? 1.f : 0.f;
        lo.w = (r == f0 + 3) ? 1.f : 0.f;
        hi.x = (r == f0 + 4) ? 1.f : 0.f;
        hi.y = (r == f0 + 5) ? 1.f : 0.f;
        hi.z = (r == f0 + 6) ? 1.f : 0.f;
        hi.w = (r == f0 + 7) ? 1.f : 0.f;
    } else {
        const u16* row = finalX + ((size_t)b * DIM + (r - NTIPS)) * NTIPS + f0;
        const ushort4 a = *reinterpret_cast<const ushort4*>(row);
        const ushort4 c = *reinterpret_cast<const ushort4*>(row + 4);
        lo.x = bf2f(a.x); lo.y = bf2f(a.y); lo.z = bf2f(a.z); lo.w = bf2f(a.w);
        hi.x = bf2f(c.x); hi.y = bf2f(c.y); hi.z = bf2f(c.z); hi.w = bf2f(c.w);
    }
    float* drow = out + ((size_t)b * TOTAL + r) * NTIPS + f0;
    *reinterpret_cast<float4*>(drow)     = lo;
    *reinterpret_cast<float4*>(drow + 4) = hi;
}

extern "C" void kernel_launch(void* const* d_in, const int* in_sizes, int n_in,
                              void* d_out, int out_size, void* d_ws, size_t ws_size,
                              hipStream_t stream) {
    const int* edge = (const int*)d_in[1];       // (BS, TOTAL, 3) int32
    float* out = (float*)d_out;

    const size_t XB = (size_t)BS * DIM * NTIPS;  // 16,711,680 u16 elems
    u16*   snapW = (u16*)d_ws;                   // ws slot (also finalX home)
    float* partials = (float*)((char*)d_ws + XB * sizeof(u16));
    int*   ctrl = (int*)(partials + NPART);

    u16* snapD = (u16*)d_out;                    // d_out scratch slot

    for (int q = 1; q <= NCHUNK; ++q) {
        chunk_kernel<<<NWG, 256, 0, stream>>>(edge, partials, ctrl,
                                              snapD, snapW, q);
        findS_kernel<<<1, 64, 0, stream>>>(partials, ctrl, q * WIDTH);
    }
    phaseC_kernel<<<NWG, 256, 0, stream>>>(edge, ctrl, snapD, snapW, snapW);
    convert_kernel<<<dim3(TOTAL, BS), 64, 0, stream>>>(snapW, out);
}